// Round 5
// baseline (320.482 us; speedup 1.0000x reference)
//
#include <hip/hip_runtime.h>
#include <stdint.h>
#include <stddef.h>

// MHA forward, MI355X gfx950. B=2 S=2048 D=1024 H=16 hd=64.
// bf16 MFMA, fp32 accum, fp32 output.

typedef __bf16 bf16_t;
typedef __bf16 bf16x8 __attribute__((ext_vector_type(8)));
typedef __bf16 bf16x4 __attribute__((ext_vector_type(4)));
typedef __bf16 bf16x2 __attribute__((ext_vector_type(2)));
typedef float  f32x4  __attribute__((ext_vector_type(4)));
typedef float  f32x16 __attribute__((ext_vector_type(16)));
typedef uint32_t u32x4 __attribute__((ext_vector_type(4)));

static constexpr float kQScale = 0.18033688011112042f; // (1/sqrt(64)) * log2(e); softmax in base-2

__device__ __forceinline__ void gload_lds16(const bf16_t* g, bf16_t* l) {
  __builtin_amdgcn_global_load_lds((__attribute__((address_space(1))) void*)(void*)g,
                                   (__attribute__((address_space(3))) void*)l, 16, 0, 0);
}

// pack two f32 -> one u32 of 2 bf16 (compiler emits v_cvt_pk_bf16_f32)
__device__ __forceinline__ uint32_t pk_bf16(float lo, float hi) {
  bf16x2 v; v[0] = (bf16_t)lo; v[1] = (bf16_t)hi;
  return __builtin_bit_cast(uint32_t, v);
}

// ---------------- K1: cast x (f32) -> xb (bf16) ----------------
__global__ __launch_bounds__(256) void cast_x_k(const float* __restrict__ x, bf16_t* __restrict__ xb) {
  int i = blockIdx.x * 256 + threadIdx.x;
  float4 v = ((const float4*)x)[i];
  bf16x4 o;
  o[0] = (bf16_t)v.x; o[1] = (bf16_t)v.y; o[2] = (bf16_t)v.z; o[3] = (bf16_t)v.w;
  ((bf16x4*)xb)[i] = o;
}

// ---------------- K2: transpose+cast weights: wT[n][k] = w[k][n] ----------------
__global__ __launch_bounds__(256) void transpose_w_k(
    const float* __restrict__ wq, const float* __restrict__ wk,
    const float* __restrict__ wv, const float* __restrict__ wo,
    bf16_t* __restrict__ wqkvT, bf16_t* __restrict__ woT) {
  __shared__ float t[64][65];
  int z = blockIdx.z;
  const float* src = z == 0 ? wq : z == 1 ? wk : z == 2 ? wv : wo;
  bf16_t* dst = z < 3 ? wqkvT + (size_t)z * 1024 * 1024 : woT;
  int n0 = blockIdx.x * 64, k0 = blockIdx.y * 64;
  int c = threadIdx.x & 63, r4 = threadIdx.x >> 6;
#pragma unroll
  for (int i = 0; i < 16; ++i) {
    int r = r4 + i * 4;
    t[r][c] = src[(size_t)(k0 + r) * 1024 + (n0 + c)];
  }
  __syncthreads();
#pragma unroll
  for (int i = 0; i < 16; ++i) {
    int r = r4 + i * 4;
    dst[(size_t)(n0 + r) * 1024 + (k0 + c)] = (bf16_t)t[c][r];
  }
}

// ---------------- K3/K6: bf16 GEMM, m97 structure (128x128 tile, BK=32) ----------------
template <int EPI>
__global__ __launch_bounds__(256) void gemm_k(
    const bf16_t* __restrict__ A, const bf16_t* __restrict__ Bw,
    bf16_t* __restrict__ Qb, bf16_t* __restrict__ Kb, bf16_t* __restrict__ Vb,
    const float* __restrict__ bq, const float* __restrict__ bk, const float* __restrict__ bv,
    float* __restrict__ outF, const float* __restrict__ bo) {
  __shared__ alignas(16) bf16_t As[128 * 32];
  __shared__ alignas(16) bf16_t Bs[128 * 32];
  const int tid = threadIdx.x;
  const int lane = tid & 63;
  const int w = tid >> 6, wr = w >> 1, wc = w & 1;
  const int brow = blockIdx.y * 128, bcol = blockIdx.x * 128;
  const int l15 = lane & 15, ko = (lane >> 4) * 8;

  f32x4 acc[4][4] = {};
  const bf16_t* Ab = A + (size_t)brow * 1024;
  const bf16_t* Bb = Bw + (size_t)bcol * 1024;

  const int e0 = tid * 8;
  const int r0 = e0 >> 5, c0 = e0 & 31;

  for (int k0 = 0; k0 < 1024; k0 += 32) {
    gload_lds16(Ab + (size_t)r0 * 1024 + k0 + c0, &As[e0]);
    gload_lds16(Ab + (size_t)(r0 + 64) * 1024 + k0 + c0, &As[e0 + 2048]);
    gload_lds16(Bb + (size_t)r0 * 1024 + k0 + c0, &Bs[e0]);
    gload_lds16(Bb + (size_t)(r0 + 64) * 1024 + k0 + c0, &Bs[e0 + 2048]);
    __syncthreads();
    bf16x8 af[4], bfg[4];
#pragma unroll
    for (int i = 0; i < 4; ++i)
      af[i] = *(const bf16x8*)&As[(wr * 64 + i * 16 + l15) * 32 + ko];
#pragma unroll
    for (int i = 0; i < 4; ++i)
      bfg[i] = *(const bf16x8*)&Bs[(wc * 64 + i * 16 + l15) * 32 + ko];
#pragma unroll
    for (int i = 0; i < 4; ++i)
#pragma unroll
      for (int j = 0; j < 4; ++j)
        acc[i][j] = __builtin_amdgcn_mfma_f32_16x16x32_bf16(af[i], bfg[j], acc[i][j], 0, 0, 0);
    __syncthreads();
  }

#pragma unroll
  for (int i = 0; i < 4; ++i) {
    const int gm0 = brow + wr * 64 + i * 16 + ((lane >> 4) << 2);
#pragma unroll
    for (int j = 0; j < 4; ++j) {
      const int gn = bcol + wc * 64 + j * 16 + l15;
      if constexpr (EPI == 0) {
        const int mat = gn >> 10;
        const int col = gn & 1023;
        bf16_t* dst = mat == 0 ? Qb : (mat == 1 ? Kb : Vb);
        const float* bias = mat == 0 ? bq : (mat == 1 ? bk : bv);
        const float scl = mat == 0 ? kQScale : 1.0f;
        const float bsv = bias[col];
        const int h = col >> 6, dd = col & 63;
#pragma unroll
        for (int r = 0; r < 4; ++r) {
          const int m = gm0 + r;
          const int b = m >> 11, s = m & 2047;
          dst[((((size_t)b * 16 + h) * 2048 + s) * 64 + dd)] = (bf16_t)((acc[i][j][r] + bsv) * scl);
        }
      } else {
        const float bsv = bo[gn];
#pragma unroll
        for (int r = 0; r < 4; ++r)
          outF[(size_t)(gm0 + r) * 1024 + gn] = acc[i][j][r] + bsv;
      }
    }
  }
}

// ---------------- K4: transpose V [bh][s][64] -> Vt [bh][64][s] ----------------
__global__ __launch_bounds__(256) void transpose_v_k(const bf16_t* __restrict__ V, bf16_t* __restrict__ Vt) {
  __shared__ bf16_t t[64][65];
  int bh = blockIdx.y, s0 = blockIdx.x * 64;
  const bf16_t* src = V + (size_t)bh * 2048 * 64;
  bf16_t* dst = Vt + (size_t)bh * 64 * 2048;
  int c = threadIdx.x & 63, r4 = threadIdx.x >> 6;
#pragma unroll
  for (int i = 0; i < 16; ++i) {
    int r = r4 + i * 4;
    t[r][c] = src[(size_t)(s0 + r) * 64 + c];
  }
  __syncthreads();
#pragma unroll
  for (int i = 0; i < 16; ++i) {
    int d = r4 + i * 4;
    dst[(size_t)d * 2048 + s0 + c] = t[c][d];
  }
}

// ---------------- K5: flash attention, 32x32 MFMA, zero-LDS inner loop, KV-split x2 ----
// Q [bh][s][64] (pre-scaled by log2e/8), K [bh][s][64], Vt [bh][64][s], all bf16.
// 8 waves/block: wave = (qsub 0..3, kvhalf 0..1). Wave owns 32 q-rows x 1024 keys
// (16 tiles of 64). End: (m,l,o) pair-merge across kv halves via LDS (one barrier).
// S^T = mfma(K,Q) 32x32x16; softmax fully in-lane + shfl_xor(32); defer-rescale THR=8;
// raw v_exp_f32; P^T B-frags via cvt_pk + shfl_xor(32)+select. O^T = mfma(V^T, P^T).
__global__ __launch_bounds__(512, 4) void attn_k(
    const bf16_t* __restrict__ Qb, const bf16_t* __restrict__ Kb,
    const bf16_t* __restrict__ Vt, bf16_t* __restrict__ O) {
  __shared__ float cmb_m[4][64];
  __shared__ float cmb_l[4][64];
  __shared__ float cmb_o[4][32][64];   // [qsub][reg][lane], stride-1 across lanes
  const int tid = threadIdx.x, lane = tid & 63, w = tid >> 6;
  const int l31 = lane & 31, hi = lane >> 5;
  const int qsub = w & 3, half = w >> 2;
  // bijective XCD-chunked swizzle: 512 blocks, 64 consecutive per XCD
  const int work = (blockIdx.x & 7) * 64 + (blockIdx.x >> 3);
  const int bh = work >> 4;
  const int q0 = (work & 15) * 128 + qsub * 32;

  const bf16_t* Qp = Qb + ((size_t)bh * 2048 + q0) * 64;
  const bf16_t* Kp = Kb + (size_t)bh * 2048 * 64 + (size_t)half * 1024 * 64;
  const bf16_t* Vp = Vt + (size_t)bh * 64 * 2048 + (size_t)half * 1024;

  // Q B-operand: col=q=l31, contraction d = ds*16 + hi*8 + j (map cancels vs K side)
  bf16x8 qf[4];
#pragma unroll
  for (int ds = 0; ds < 4; ++ds)
    qf[ds] = *(const bf16x8*)&Qp[(size_t)l31 * 64 + ds * 16 + hi * 8];

  f32x16 o0 = {}, o1 = {};
  float mx = -1e30f, li = 0.0f;

  // advancing lane-base pointers (imm-offset friendly)
  const bf16_t* pK0 = Kp + (size_t)l31 * 64 + hi * 8;            // K rows st=0; +ds*16 imm
  const bf16_t* pK1 = pK0 + 32 * 64;                              // K rows st=1
  const bf16_t* pV0 = Vp + (size_t)l31 * 2048 + hi * 8;           // V rows dt=0; +ks*16 imm
  const bf16_t* pV1 = pV0 + 32 * 2048;                            // V rows dt=1

  bf16x8 kc[2][4], kn[2][4];
#pragma unroll
  for (int ds = 0; ds < 4; ++ds) {
    kc[0][ds] = *(const bf16x8*)(pK0 + ds * 16);
    kc[1][ds] = *(const bf16x8*)(pK1 + ds * 16);
  }

  auto body = [&](bf16x8 (&kcur)[2][4], bf16x8 (&knxt)[2][4]) {
    // prefetch V(t) and K(t+1); last K prefetch reads past the half (valid ws memory, unused)
    bf16x8 vf[2][4];
#pragma unroll
    for (int ks = 0; ks < 4; ++ks) {
      vf[0][ks] = *(const bf16x8*)(pV0 + ks * 16);
      vf[1][ks] = *(const bf16x8*)(pV1 + ks * 16);
    }
    pV0 += 64; pV1 += 64;
    pK0 += 64 * 64; pK1 += 64 * 64;
#pragma unroll
    for (int ds = 0; ds < 4; ++ds) {
      knxt[0][ds] = *(const bf16x8*)(pK0 + ds * 16);
      knxt[1][ds] = *(const bf16x8*)(pK1 + ds * 16);
    }

    // S^T = K Q^T (Q pre-scaled)
    f32x16 s0 = {}, s1 = {};
    __builtin_amdgcn_s_setprio(1);
#pragma unroll
    for (int ds = 0; ds < 4; ++ds)
      s0 = __builtin_amdgcn_mfma_f32_32x32x16_bf16(kcur[0][ds], qf[ds], s0, 0, 0, 0);
#pragma unroll
    for (int ds = 0; ds < 4; ++ds)
      s1 = __builtin_amdgcn_mfma_f32_32x32x16_bf16(kcur[1][ds], qf[ds], s1, 0, 0, 0);
    __builtin_amdgcn_s_setprio(0);

    // tile max, tree reduce (depth 5) + cross-half
    float m8[8];
#pragma unroll
    for (int r = 0; r < 8; ++r)
      m8[r] = fmaxf(fmaxf(s0[r], s0[r + 8]), fmaxf(s1[r], s1[r + 8]));
    float m4a = fmaxf(m8[0], m8[4]), m4b = fmaxf(m8[1], m8[5]);
    float m4c = fmaxf(m8[2], m8[6]), m4d = fmaxf(m8[3], m8[7]);
    float tmax = fmaxf(fmaxf(m4a, m4b), fmaxf(m4c, m4d));
    tmax = fmaxf(tmax, __shfl_xor(tmax, 32));

    // defer-rescale: only rescale when some lane's max grew past mx+8 (P <= 2^8)
    if (__any(tmax > mx + 8.0f)) {
      const float mn = fmaxf(mx, tmax);
      const float corr = __builtin_amdgcn_exp2f(mx - mn);
      mx = mn;
      li *= corr;
#pragma unroll
      for (int r = 0; r < 16; ++r) { o0[r] *= corr; o1[r] *= corr; }
    }

    // p = exp2(s - mx), 4-way partial sums
    float ra = 0.f, rb = 0.f, rc = 0.f, rd = 0.f;
#pragma unroll
    for (int r = 0; r < 4; ++r) {
      float p0 = __builtin_amdgcn_exp2f(s0[r] - mx);       s0[r] = p0; ra += p0;
      float p1 = __builtin_amdgcn_exp2f(s0[r + 4] - mx);   s0[r + 4] = p1; rb += p1;
      float p2 = __builtin_amdgcn_exp2f(s0[r + 8] - mx);   s0[r + 8] = p2; rc += p2;
      float p3 = __builtin_amdgcn_exp2f(s0[r + 12] - mx);  s0[r + 12] = p3; rd += p3;
      float p4 = __builtin_amdgcn_exp2f(s1[r] - mx);       s1[r] = p4; ra += p4;
      float p5 = __builtin_amdgcn_exp2f(s1[r + 4] - mx);   s1[r + 4] = p5; rb += p5;
      float p6 = __builtin_amdgcn_exp2f(s1[r + 8] - mx);   s1[r + 8] = p6; rc += p6;
      float p7 = __builtin_amdgcn_exp2f(s1[r + 12] - mx);  s1[r + 12] = p7; rd += p7;
    }
    float rs = (ra + rb) + (rc + rd);
    rs += __shfl_xor(rs, 32);
    li += rs;

    // pack P -> bf16 words: word (g,c) holds keys(local32) (8g+4hi+2c, +1)
    uint32_t pw0[8], pw1[8];
#pragma unroll
    for (int g = 0; g < 4; ++g) {
      pw0[g * 2 + 0] = pk_bf16(s0[4 * g + 0], s0[4 * g + 1]);
      pw0[g * 2 + 1] = pk_bf16(s0[4 * g + 2], s0[4 * g + 3]);
      pw1[g * 2 + 0] = pk_bf16(s1[4 * g + 0], s1[4 * g + 1]);
      pw1[g * 2 + 1] = pk_bf16(s1[4 * g + 2], s1[4 * g + 3]);
    }

    // PV: O^T += V^T P^T; B-frag element (hi,j) holds local16 key 8hi+j
#pragma unroll
    for (int st = 0; st < 2; ++st) {
      uint32_t (&pw)[8] = st ? pw1 : pw0;
#pragma unroll
      for (int ks = 0; ks < 2; ++ks) {
        const uint32_t A0 = pw[(2 * ks) * 2 + 0], A1 = pw[(2 * ks) * 2 + 1];
        const uint32_t B0 = pw[(2 * ks + 1) * 2 + 0], B1 = pw[(2 * ks + 1) * 2 + 1];
        const uint32_t Z0 = hi ? A0 : B0;
        const uint32_t Z1 = hi ? A1 : B1;
        const uint32_t sZ0 = (uint32_t)__shfl_xor((int)Z0, 32);
        const uint32_t sZ1 = (uint32_t)__shfl_xor((int)Z1, 32);
        u32x4 fw;
        fw[0] = hi ? sZ0 : A0;
        fw[1] = hi ? sZ1 : A1;
        fw[2] = hi ? B0 : sZ0;
        fw[3] = hi ? B1 : sZ1;
        const bf16x8 pf = __builtin_bit_cast(bf16x8, fw);
        __builtin_amdgcn_s_setprio(1);
        o0 = __builtin_amdgcn_mfma_f32_32x32x16_bf16(vf[0][st * 2 + ks], pf, o0, 0, 0, 0);
        o1 = __builtin_amdgcn_mfma_f32_32x32x16_bf16(vf[1][st * 2 + ks], pf, o1, 0, 0, 0);
        __builtin_amdgcn_s_setprio(0);
      }
    }
  };

#pragma unroll 1
  for (int t = 0; t < 16; t += 2) {
    body(kc, kn);
    body(kn, kc);
  }

  // merge kv-halves: half 1 publishes, half 0 combines and stores
  if (half) {
    cmb_m[qsub][lane] = mx;
    cmb_l[qsub][lane] = li;
#pragma unroll
    for (int r = 0; r < 16; ++r) {
      cmb_o[qsub][r][lane] = o0[r];
      cmb_o[qsub][16 + r][lane] = o1[r];
    }
  }
  __syncthreads();
  if (!half) {
    const float mb = cmb_m[qsub][lane];
    const float lb = cmb_l[qsub][lane];
    const float M = fmaxf(mx, mb);
    const float ca = __builtin_amdgcn_exp2f(mx - M);
    const float cb = __builtin_amdgcn_exp2f(mb - M);
    const float L = li * ca + lb * cb;
    const float inv = 1.0f / L;
    const float fa = ca * inv, fb = cb * inv;
    const int b = bh >> 4, h = bh & 15;
    const size_t row = (size_t)b * 2048 + q0 + l31;
#pragma unroll
    for (int g = 0; g < 4; ++g) {
      bf16x4 p0, p1;
#pragma unroll
      for (int r = 0; r < 4; ++r) {
        p0[r] = (bf16_t)(o0[4 * g + r] * fa + cmb_o[qsub][4 * g + r][lane] * fb);
        p1[r] = (bf16_t)(o1[4 * g + r] * fa + cmb_o[qsub][16 + 4 * g + r][lane] * fb);
      }
      *(bf16x4*)&O[row * 1024 + h * 64 + 0  + g * 8 + hi * 4] = p0;
      *(bf16x4*)&O[row * 1024 + h * 64 + 32 + g * 8 + hi * 4] = p1;
    }
  }
}

// ---------------- launch ----------------
extern "C" void kernel_launch(void* const* d_in, const int* in_sizes, int n_in,
                              void* d_out, int out_size, void* d_ws, size_t ws_size,
                              hipStream_t stream) {
  const float* x  = (const float*)d_in[0];
  const float* wq = (const float*)d_in[1];
  const float* bq = (const float*)d_in[2];
  const float* wk = (const float*)d_in[3];
  const float* bk = (const float*)d_in[4];
  const float* wv = (const float*)d_in[5];
  const float* bv = (const float*)d_in[6];
  const float* wo = (const float*)d_in[7];
  const float* bo = (const float*)d_in[8];
  float* out = (float*)d_out;

  if (ws_size < ((size_t)48 << 20)) return;  // need 48MB scratch
  char* ws = (char*)d_ws;
  bf16_t* xb  = (bf16_t*)(ws);                     // 8MB x bf16 [4096][1024]; reused as O after proj
  bf16_t* wT  = (bf16_t*)(ws + ((size_t)8 << 20)); // 6MB wqkvT [3072][1024] + 2MB woT
  bf16_t* woT = wT + (size_t)3072 * 1024;
  bf16_t* Qb  = (bf16_t*)(ws + ((size_t)16 << 20)); // [2][16][2048][64] bf16
  bf16_t* Kb  = (bf16_t*)(ws + ((size_t)24 << 20));
  bf16_t* Vb  = (bf16_t*)(ws + ((size_t)32 << 20));
  bf16_t* Vt  = (bf16_t*)(ws + ((size_t)40 << 20)); // [2][16][64][2048]
  bf16_t* O   = xb;

  cast_x_k<<<4096, 256, 0, stream>>>(x, xb);
  transpose_w_k<<<dim3(16, 16, 4), 256, 0, stream>>>(wq, wk, wv, wo, wT, woT);
  gemm_k<0><<<dim3(24, 32), 256, 0, stream>>>(xb, wT, Qb, Kb, Vb, bq, bk, bv, nullptr, nullptr);
  transpose_v_k<<<dim3(32, 32), 256, 0, stream>>>(Vb, Vt);
  attn_k<<<512, 512, 0, stream>>>(Qb, Kb, Vt, O);
  gemm_k<1><<<dim3(8, 32), 256, 0, stream>>>(O, woT, nullptr, nullptr, nullptr,
                                             nullptr, nullptr, nullptr, out, bo);
}

// Round 6
// 132.732 us; speedup vs baseline: 2.4145x; 2.4145x over previous
//
#include <hip/hip_runtime.h>
#include <stdint.h>
#include <stddef.h>

// MHA forward, MI355X gfx950. B=2 S=2048 D=1024 H=16 hd=64.
// bf16 MFMA, fp32 accum, fp32 output.

typedef __bf16 bf16_t;
typedef __bf16 bf16x8 __attribute__((ext_vector_type(8)));
typedef __bf16 bf16x4 __attribute__((ext_vector_type(4)));
typedef __bf16 bf16x2 __attribute__((ext_vector_type(2)));
typedef float  f32x4  __attribute__((ext_vector_type(4)));
typedef float  f32x16 __attribute__((ext_vector_type(16)));
typedef uint32_t u32x4 __attribute__((ext_vector_type(4)));

static constexpr float kQScale = 0.18033688011112042f; // (1/sqrt(64)) * log2(e); softmax in base-2

__device__ __forceinline__ void gload_lds16(const bf16_t* g, bf16_t* l) {
  __builtin_amdgcn_global_load_lds((__attribute__((address_space(1))) void*)(void*)g,
                                   (__attribute__((address_space(3))) void*)l, 16, 0, 0);
}

// pack two f32 -> one u32 of 2 bf16 (compiler emits v_cvt_pk_bf16_f32)
__device__ __forceinline__ uint32_t pk_bf16(float lo, float hi) {
  bf16x2 v; v[0] = (bf16_t)lo; v[1] = (bf16_t)hi;
  return __builtin_bit_cast(uint32_t, v);
}

// ---------------- K1: cast x (f32) -> xb (bf16) ----------------
__global__ __launch_bounds__(256) void cast_x_k(const float* __restrict__ x, bf16_t* __restrict__ xb) {
  int i = blockIdx.x * 256 + threadIdx.x;
  float4 v = ((const float4*)x)[i];
  bf16x4 o;
  o[0] = (bf16_t)v.x; o[1] = (bf16_t)v.y; o[2] = (bf16_t)v.z; o[3] = (bf16_t)v.w;
  ((bf16x4*)xb)[i] = o;
}

// ---------------- K2: transpose+cast weights: wT[n][k] = w[k][n] ----------------
__global__ __launch_bounds__(256) void transpose_w_k(
    const float* __restrict__ wq, const float* __restrict__ wk,
    const float* __restrict__ wv, const float* __restrict__ wo,
    bf16_t* __restrict__ wqkvT, bf16_t* __restrict__ woT) {
  __shared__ float t[64][65];
  int z = blockIdx.z;
  const float* src = z == 0 ? wq : z == 1 ? wk : z == 2 ? wv : wo;
  bf16_t* dst = z < 3 ? wqkvT + (size_t)z * 1024 * 1024 : woT;
  int n0 = blockIdx.x * 64, k0 = blockIdx.y * 64;
  int c = threadIdx.x & 63, r4 = threadIdx.x >> 6;
#pragma unroll
  for (int i = 0; i < 16; ++i) {
    int r = r4 + i * 4;
    t[r][c] = src[(size_t)(k0 + r) * 1024 + (n0 + c)];
  }
  __syncthreads();
#pragma unroll
  for (int i = 0; i < 16; ++i) {
    int r = r4 + i * 4;
    dst[(size_t)(n0 + r) * 1024 + (k0 + c)] = (bf16_t)t[c][r];
  }
}

// ---------------- K3/K6: bf16 GEMM, m97 structure (128x128 tile, BK=32) ----------------
template <int EPI>
__global__ __launch_bounds__(256) void gemm_k(
    const bf16_t* __restrict__ A, const bf16_t* __restrict__ Bw,
    bf16_t* __restrict__ Qb, bf16_t* __restrict__ Kb, bf16_t* __restrict__ Vb,
    const float* __restrict__ bq, const float* __restrict__ bk, const float* __restrict__ bv,
    float* __restrict__ outF, const float* __restrict__ bo) {
  __shared__ alignas(16) bf16_t As[128 * 32];
  __shared__ alignas(16) bf16_t Bs[128 * 32];
  const int tid = threadIdx.x;
  const int lane = tid & 63;
  const int w = tid >> 6, wr = w >> 1, wc = w & 1;
  const int brow = blockIdx.y * 128, bcol = blockIdx.x * 128;
  const int l15 = lane & 15, ko = (lane >> 4) * 8;

  f32x4 acc[4][4] = {};
  const bf16_t* Ab = A + (size_t)brow * 1024;
  const bf16_t* Bb = Bw + (size_t)bcol * 1024;

  const int e0 = tid * 8;
  const int r0 = e0 >> 5, c0 = e0 & 31;

  for (int k0 = 0; k0 < 1024; k0 += 32) {
    gload_lds16(Ab + (size_t)r0 * 1024 + k0 + c0, &As[e0]);
    gload_lds16(Ab + (size_t)(r0 + 64) * 1024 + k0 + c0, &As[e0 + 2048]);
    gload_lds16(Bb + (size_t)r0 * 1024 + k0 + c0, &Bs[e0]);
    gload_lds16(Bb + (size_t)(r0 + 64) * 1024 + k0 + c0, &Bs[e0 + 2048]);
    __syncthreads();
    bf16x8 af[4], bfg[4];
#pragma unroll
    for (int i = 0; i < 4; ++i)
      af[i] = *(const bf16x8*)&As[(wr * 64 + i * 16 + l15) * 32 + ko];
#pragma unroll
    for (int i = 0; i < 4; ++i)
      bfg[i] = *(const bf16x8*)&Bs[(wc * 64 + i * 16 + l15) * 32 + ko];
#pragma unroll
    for (int i = 0; i < 4; ++i)
#pragma unroll
      for (int j = 0; j < 4; ++j)
        acc[i][j] = __builtin_amdgcn_mfma_f32_16x16x32_bf16(af[i], bfg[j], acc[i][j], 0, 0, 0);
    __syncthreads();
  }

#pragma unroll
  for (int i = 0; i < 4; ++i) {
    const int gm0 = brow + wr * 64 + i * 16 + ((lane >> 4) << 2);
#pragma unroll
    for (int j = 0; j < 4; ++j) {
      const int gn = bcol + wc * 64 + j * 16 + l15;
      if constexpr (EPI == 0) {
        const int mat = gn >> 10;
        const int col = gn & 1023;
        bf16_t* dst = mat == 0 ? Qb : (mat == 1 ? Kb : Vb);
        const float* bias = mat == 0 ? bq : (mat == 1 ? bk : bv);
        const float scl = mat == 0 ? kQScale : 1.0f;
        const float bsv = bias[col];
        const int h = col >> 6, dd = col & 63;
#pragma unroll
        for (int r = 0; r < 4; ++r) {
          const int m = gm0 + r;
          const int b = m >> 11, s = m & 2047;
          dst[((((size_t)b * 16 + h) * 2048 + s) * 64 + dd)] = (bf16_t)((acc[i][j][r] + bsv) * scl);
        }
      } else {
        const float bsv = bo[gn];
#pragma unroll
        for (int r = 0; r < 4; ++r)
          outF[(size_t)(gm0 + r) * 1024 + gn] = acc[i][j][r] + bsv;
      }
    }
  }
}

// ---------------- K4: transpose V [bh][s][64] -> Vt [bh][64][s] ----------------
__global__ __launch_bounds__(256) void transpose_v_k(const bf16_t* __restrict__ V, bf16_t* __restrict__ Vt) {
  __shared__ bf16_t t[64][65];
  int bh = blockIdx.y, s0 = blockIdx.x * 64;
  const bf16_t* src = V + (size_t)bh * 2048 * 64;
  bf16_t* dst = Vt + (size_t)bh * 64 * 2048;
  int c = threadIdx.x & 63, r4 = threadIdx.x >> 6;
#pragma unroll
  for (int i = 0; i < 16; ++i) {
    int r = r4 + i * 4;
    t[r][c] = src[(size_t)(s0 + r) * 64 + c];
  }
  __syncthreads();
#pragma unroll
  for (int i = 0; i < 16; ++i) {
    int d = r4 + i * 4;
    dst[(size_t)d * 2048 + s0 + c] = t[c][d];
  }
}

// ---------------- K5: flash attention, 32x32 MFMA, LDS-shared K/V tiles ----------------
// Q [bh][s][64] (pre-scaled by log2e/8), K [bh][s][64], Vt [bh][64][s], all bf16.
// Block = 4 waves = 128 q-rows; K/V tiles (64 keys) staged once per block in LDS
// (double-buffered, global_load_lds w16, XOR-swizzled source+read per rule #21)
// -> K/V L2 traffic cut 4x vs per-wave reads (the round-2/4 130us floor).
// S^T = mfma(K,Q) 32x32x16; in-register softmax (tree max, raw exp2, defer-rescale);
// P^T B-frags via cvt_pk + shfl_xor(32)+select (verified r4). O^T = mfma(V^T, P^T).
__global__ __launch_bounds__(256, 2) void attn_k(
    const bf16_t* __restrict__ Qb, const bf16_t* __restrict__ Kb,
    const bf16_t* __restrict__ Vt, bf16_t* __restrict__ O) {
  __shared__ alignas(16) bf16_t Ksm[2][4096];   // [buf][64 rows][64 elems] swizzled
  __shared__ alignas(16) bf16_t Vsm[2][4096];   // [buf][64 d-rows][64 keys] swizzled
  const int tid = threadIdx.x, lane = tid & 63, w = tid >> 6;
  const int l31 = lane & 31, hi = lane >> 5;
  // bijective XCD-chunked swizzle: 512 blocks, 64 consecutive per XCD -> 4 heads/XCD L2
  const int work = (blockIdx.x & 7) * 64 + (blockIdx.x >> 3);
  const int bh = work >> 4;
  const int q0 = (work & 15) * 128 + w * 32;

  const bf16_t* Qp = Qb + ((size_t)bh * 2048 + q0) * 64;

  // ---- staging sources (per-thread, advancing). Tile = 8KB, 512 x 16B chunks.
  // Thread covers chunks i = w*64+lane (+256). row=i>>3, c=i&7; source chunk c^(row&7).
  const int chunk0 = w * 64 + lane;
  const int srow = chunk0 >> 3;                       // 0..31 (r=1 adds 32; &7 invariant)
  const int swzc = (chunk0 & 7) ^ (srow & 7);
  const char* srcK0 = (const char*)(Kb + (size_t)bh * 2048 * 64) + srow * 128 + swzc * 16;
  const char* srcK1 = srcK0 + 32 * 128;
  const char* srcV0 = (const char*)(Vt + (size_t)bh * 64 * 2048) + srow * 4096 + swzc * 16;
  const char* srcV1 = srcV0 + 32 * 4096;

  auto stage = [&](int buf) {   // 4 x gload_lds16; dest = wave-uniform base + lane*16
    bf16_t* kb = &Ksm[buf][w * 512];
    bf16_t* vb = &Vsm[buf][w * 512];
    gload_lds16((const bf16_t*)srcK0, kb);
    gload_lds16((const bf16_t*)srcK1, kb + 2048);
    gload_lds16((const bf16_t*)srcV0, vb);
    gload_lds16((const bf16_t*)srcV1, vb + 2048);
    srcK0 += 8192; srcK1 += 8192;                     // next 64 key rows
    srcV0 += 128;  srcV1 += 128;                      // next 64 keys within d-rows
  };

  // ---- fragment read bases (lane-constant; +st/dt*2048 +buf*4096 are immediates)
  const int xorv = l31 & 7;
  const bf16_t* kcb[4];
  const bf16_t* vcb[4];
#pragma unroll
  for (int j = 0; j < 4; ++j) {
    const int co = ((j * 2 + hi) ^ xorv) * 8;
    kcb[j] = &Ksm[0][l31 * 64 + co];
    vcb[j] = &Vsm[0][l31 * 64 + co];
  }

  // Q B-operand: col=q=l31, contraction d = ds*16 + hi*8 + j (map cancels vs K side)
  bf16x8 qf[4];
#pragma unroll
  for (int ds = 0; ds < 4; ++ds)
    qf[ds] = *(const bf16x8*)&Qp[(size_t)l31 * 64 + ds * 16 + hi * 8];

  f32x16 o0 = {}, o1 = {};
  float mx = -1e30f, li = 0.0f;

  auto tile_body = [&](int buf) {
    const int bo = buf * 4096;
    // K fragments from LDS
    bf16x8 kf0[4], kf1[4];
#pragma unroll
    for (int ds = 0; ds < 4; ++ds) {
      kf0[ds] = *(const bf16x8*)(kcb[ds] + bo);
      kf1[ds] = *(const bf16x8*)(kcb[ds] + bo + 2048);
    }
    // S^T = K Q^T (Q pre-scaled)
    f32x16 s0 = {}, s1 = {};
    __builtin_amdgcn_s_setprio(1);
#pragma unroll
    for (int ds = 0; ds < 4; ++ds)
      s0 = __builtin_amdgcn_mfma_f32_32x32x16_bf16(kf0[ds], qf[ds], s0, 0, 0, 0);
#pragma unroll
    for (int ds = 0; ds < 4; ++ds)
      s1 = __builtin_amdgcn_mfma_f32_32x32x16_bf16(kf1[ds], qf[ds], s1, 0, 0, 0);
    __builtin_amdgcn_s_setprio(0);
    // V fragments (issue early; consumed after softmax)
    bf16x8 vf0[4], vf1[4];
#pragma unroll
    for (int ks = 0; ks < 4; ++ks) {
      vf0[ks] = *(const bf16x8*)(vcb[ks] + bo);
      vf1[ks] = *(const bf16x8*)(vcb[ks] + bo + 2048);
    }

    // tile max, tree reduce + cross-half
    float m8[8];
#pragma unroll
    for (int r = 0; r < 8; ++r)
      m8[r] = fmaxf(fmaxf(s0[r], s0[r + 8]), fmaxf(s1[r], s1[r + 8]));
    float m4a = fmaxf(m8[0], m8[4]), m4b = fmaxf(m8[1], m8[5]);
    float m4c = fmaxf(m8[2], m8[6]), m4d = fmaxf(m8[3], m8[7]);
    float tmax = fmaxf(fmaxf(m4a, m4b), fmaxf(m4c, m4d));
    tmax = fmaxf(tmax, __shfl_xor(tmax, 32));

    // defer-rescale: only rescale when some lane's max grew past mx+8 (P <= 2^8)
    if (__any(tmax > mx + 8.0f)) {
      const float mn = fmaxf(mx, tmax);
      const float corr = __builtin_amdgcn_exp2f(mx - mn);
      mx = mn;
      li *= corr;
#pragma unroll
      for (int r = 0; r < 16; ++r) { o0[r] *= corr; o1[r] *= corr; }
    }

    // p = exp2(s - mx), 4-way partial sums
    float ra = 0.f, rb = 0.f, rc = 0.f, rd = 0.f;
#pragma unroll
    for (int r = 0; r < 4; ++r) {
      float p0 = __builtin_amdgcn_exp2f(s0[r] - mx);       s0[r] = p0; ra += p0;
      float p1 = __builtin_amdgcn_exp2f(s0[r + 4] - mx);   s0[r + 4] = p1; rb += p1;
      float p2 = __builtin_amdgcn_exp2f(s0[r + 8] - mx);   s0[r + 8] = p2; rc += p2;
      float p3 = __builtin_amdgcn_exp2f(s0[r + 12] - mx);  s0[r + 12] = p3; rd += p3;
      float p4 = __builtin_amdgcn_exp2f(s1[r] - mx);       s1[r] = p4; ra += p4;
      float p5 = __builtin_amdgcn_exp2f(s1[r + 4] - mx);   s1[r + 4] = p5; rb += p5;
      float p6 = __builtin_amdgcn_exp2f(s1[r + 8] - mx);   s1[r + 8] = p6; rc += p6;
      float p7 = __builtin_amdgcn_exp2f(s1[r + 12] - mx);  s1[r + 12] = p7; rd += p7;
    }
    float rs = (ra + rb) + (rc + rd);
    rs += __shfl_xor(rs, 32);
    li += rs;

    // pack P -> bf16 words: word (g,c) holds keys(local32) (8g+4hi+2c, +1)
    uint32_t pw0[8], pw1[8];
#pragma unroll
    for (int g = 0; g < 4; ++g) {
      pw0[g * 2 + 0] = pk_bf16(s0[4 * g + 0], s0[4 * g + 1]);
      pw0[g * 2 + 1] = pk_bf16(s0[4 * g + 2], s0[4 * g + 3]);
      pw1[g * 2 + 0] = pk_bf16(s1[4 * g + 0], s1[4 * g + 1]);
      pw1[g * 2 + 1] = pk_bf16(s1[4 * g + 2], s1[4 * g + 3]);
    }

    // PV: O^T += V^T P^T; B-frag element (hi,j) holds local16 key 8hi+j
#pragma unroll
    for (int st = 0; st < 2; ++st) {
      uint32_t (&pw)[8] = st ? pw1 : pw0;
#pragma unroll
      for (int ks = 0; ks < 2; ++ks) {
        const uint32_t A0 = pw[(2 * ks) * 2 + 0], A1 = pw[(2 * ks) * 2 + 1];
        const uint32_t B0 = pw[(2 * ks + 1) * 2 + 0], B1 = pw[(2 * ks + 1) * 2 + 1];
        const uint32_t Z0 = hi ? A0 : B0;
        const uint32_t Z1 = hi ? A1 : B1;
        const uint32_t sZ0 = (uint32_t)__shfl_xor((int)Z0, 32);
        const uint32_t sZ1 = (uint32_t)__shfl_xor((int)Z1, 32);
        u32x4 fw;
        fw[0] = hi ? sZ0 : A0;
        fw[1] = hi ? sZ1 : A1;
        fw[2] = hi ? B0 : sZ0;
        fw[3] = hi ? B1 : sZ1;
        const bf16x8 pf = __builtin_bit_cast(bf16x8, fw);
        __builtin_amdgcn_s_setprio(1);
        o0 = __builtin_amdgcn_mfma_f32_32x32x16_bf16(vf0[st * 2 + ks], pf, o0, 0, 0, 0);
        o1 = __builtin_amdgcn_mfma_f32_32x32x16_bf16(vf1[st * 2 + ks], pf, o1, 0, 0, 0);
        __builtin_amdgcn_s_setprio(0);
      }
    }
  };

  // ---- pipeline: stage t+1 while computing t; one barrier per tile (drains vmcnt)
  stage(0);
  __syncthreads();
#pragma unroll 1
  for (int t = 0; t < 32; t += 2) {
    stage(1);                 // tile t+1 -> buf1 (t+1 <= 31 always)
    tile_body(0);
    __syncthreads();
    if (t + 2 < 32) stage(0); // tile t+2 -> buf0
    tile_body(1);
    if (t + 2 < 32) __syncthreads();
  }

  // epilogue: O^T C-layout: col=q=l31, row d = 32dt + 8g + 4hi + r
  const int b = bh >> 4, h = bh & 15;
  const float inv = 1.0f / li;
  const size_t row = (size_t)b * 2048 + q0 + l31;
#pragma unroll
  for (int g = 0; g < 4; ++g) {
    bf16x4 p0, p1;
#pragma unroll
    for (int r = 0; r < 4; ++r) {
      p0[r] = (bf16_t)(o0[4 * g + r] * inv);
      p1[r] = (bf16_t)(o1[4 * g + r] * inv);
    }
    *(bf16x4*)&O[row * 1024 + h * 64 + 0  + g * 8 + hi * 4] = p0;
    *(bf16x4*)&O[row * 1024 + h * 64 + 32 + g * 8 + hi * 4] = p1;
  }
}

// ---------------- launch ----------------
extern "C" void kernel_launch(void* const* d_in, const int* in_sizes, int n_in,
                              void* d_out, int out_size, void* d_ws, size_t ws_size,
                              hipStream_t stream) {
  const float* x  = (const float*)d_in[0];
  const float* wq = (const float*)d_in[1];
  const float* bq = (const float*)d_in[2];
  const float* wk = (const float*)d_in[3];
  const float* bk = (const float*)d_in[4];
  const float* wv = (const float*)d_in[5];
  const float* bv = (const float*)d_in[6];
  const float* wo = (const float*)d_in[7];
  const float* bo = (const float*)d_in[8];
  float* out = (float*)d_out;

  if (ws_size < ((size_t)48 << 20)) return;  // need 48MB scratch
  char* ws = (char*)d_ws;
  bf16_t* xb  = (bf16_t*)(ws);                     // 8MB x bf16 [4096][1024]; reused as O after proj
  bf16_t* wT  = (bf16_t*)(ws + ((size_t)8 << 20)); // 6MB wqkvT [3072][1024] + 2MB woT
  bf16_t* woT = wT + (size_t)3072 * 1024;
  bf16_t* Qb  = (bf16_t*)(ws + ((size_t)16 << 20)); // [2][16][2048][64] bf16
  bf16_t* Kb  = (bf16_t*)(ws + ((size_t)24 << 20));
  bf16_t* Vb  = (bf16_t*)(ws + ((size_t)32 << 20));
  bf16_t* Vt  = (bf16_t*)(ws + ((size_t)40 << 20)); // [2][16][64][2048]
  bf16_t* O   = xb;

  cast_x_k<<<4096, 256, 0, stream>>>(x, xb);
  transpose_w_k<<<dim3(16, 16, 4), 256, 0, stream>>>(wq, wk, wv, wo, wT, woT);
  gemm_k<0><<<dim3(24, 32), 256, 0, stream>>>(xb, wT, Qb, Kb, Vb, bq, bk, bv, nullptr, nullptr);
  transpose_v_k<<<dim3(32, 32), 256, 0, stream>>>(Vb, Vt);
  attn_k<<<512, 256, 0, stream>>>(Qb, Kb, Vt, O);
  gemm_k<1><<<dim3(8, 32), 256, 0, stream>>>(O, woT, nullptr, nullptr, nullptr,
                                             nullptr, nullptr, nullptr, out, bo);
}

// Round 7
// 122.654 us; speedup vs baseline: 2.6129x; 1.0822x over previous
//
#include <hip/hip_runtime.h>
#include <stdint.h>
#include <stddef.h>

// MHA forward, MI355X gfx950. B=2 S=2048 D=1024 H=16 hd=64.
// bf16 MFMA, fp32 accum, fp32 output.

typedef __bf16 bf16_t;
typedef __bf16 bf16x8 __attribute__((ext_vector_type(8)));
typedef __bf16 bf16x4 __attribute__((ext_vector_type(4)));
typedef __bf16 bf16x2 __attribute__((ext_vector_type(2)));
typedef float  f32x4  __attribute__((ext_vector_type(4)));
typedef float  f32x16 __attribute__((ext_vector_type(16)));
typedef uint32_t u32x4 __attribute__((ext_vector_type(4)));

static constexpr float kQScale = 0.18033688011112042f; // (1/sqrt(64)) * log2(e); softmax in base-2

__device__ __forceinline__ void gload_lds16(const bf16_t* g, bf16_t* l) {
  __builtin_amdgcn_global_load_lds((__attribute__((address_space(1))) void*)(void*)g,
                                   (__attribute__((address_space(3))) void*)l, 16, 0, 0);
}

// pack two f32 -> one u32 of 2 bf16 (compiler emits v_cvt_pk_bf16_f32)
__device__ __forceinline__ uint32_t pk_bf16(float lo, float hi) {
  bf16x2 v; v[0] = (bf16_t)lo; v[1] = (bf16_t)hi;
  return __builtin_bit_cast(uint32_t, v);
}

// ---------------- K1: prep — weights transpose+cast (z<4) and x cast (z==4) ----------
__global__ __launch_bounds__(256) void prep_k(
    const float* __restrict__ x, bf16_t* __restrict__ xb,
    const float* __restrict__ wq, const float* __restrict__ wk,
    const float* __restrict__ wv, const float* __restrict__ wo,
    bf16_t* __restrict__ wqkvT, bf16_t* __restrict__ woT) {
  __shared__ float t[64][65];
  const int z = blockIdx.z;
  if (z == 4) {
    // cast x: 1,048,576 float4s over 256 blocks x 256 threads x 16
    const int blk = blockIdx.y * 16 + blockIdx.x;
#pragma unroll
    for (int c = 0; c < 16; ++c) {
      const int i = c * 65536 + blk * 256 + threadIdx.x;
      float4 v = ((const float4*)x)[i];
      bf16x4 o;
      o[0] = (bf16_t)v.x; o[1] = (bf16_t)v.y; o[2] = (bf16_t)v.z; o[3] = (bf16_t)v.w;
      ((bf16x4*)xb)[i] = o;
    }
    return;
  }
  const float* src = z == 0 ? wq : z == 1 ? wk : z == 2 ? wv : wo;
  bf16_t* dst = z < 3 ? wqkvT + (size_t)z * 1024 * 1024 : woT;
  int n0 = blockIdx.x * 64, k0 = blockIdx.y * 64;
  int c = threadIdx.x & 63, r4 = threadIdx.x >> 6;
#pragma unroll
  for (int i = 0; i < 16; ++i) {
    int r = r4 + i * 4;
    t[r][c] = src[(size_t)(k0 + r) * 1024 + (n0 + c)];
  }
  __syncthreads();
#pragma unroll
  for (int i = 0; i < 16; ++i) {
    int r = r4 + i * 4;
    dst[(size_t)(n0 + r) * 1024 + (k0 + c)] = (bf16_t)t[c][r];
  }
}

// ---------------- K2: QKV GEMM, m97 structure (128x128 tile, BK=32) ----------------
// A: [4096][1024] bf16. Bw: [3072][1024] bf16 (row n = output col, contiguous k).
// Epilogue -> Q [bh][s][64] (+bias, *kQScale), K [bh][s][64] (+bias),
//             V^T [bh][64][s] (+bias)  — V transpose fused (4 contiguous s per frag).
__global__ __launch_bounds__(256) void gemm_qkv_k(
    const bf16_t* __restrict__ A, const bf16_t* __restrict__ Bw,
    bf16_t* __restrict__ Qb, bf16_t* __restrict__ Kb, bf16_t* __restrict__ Vt,
    const float* __restrict__ bq, const float* __restrict__ bk, const float* __restrict__ bv) {
  __shared__ alignas(16) bf16_t As[128 * 32];
  __shared__ alignas(16) bf16_t Bs[128 * 32];
  const int tid = threadIdx.x;
  const int lane = tid & 63;
  const int w = tid >> 6, wr = w >> 1, wc = w & 1;
  const int brow = blockIdx.y * 128, bcol = blockIdx.x * 128;
  const int l15 = lane & 15, ko = (lane >> 4) * 8;

  f32x4 acc[4][4] = {};
  const bf16_t* Ab = A + (size_t)brow * 1024;
  const bf16_t* Bb = Bw + (size_t)bcol * 1024;

  const int e0 = tid * 8;
  const int r0 = e0 >> 5, c0 = e0 & 31;

  for (int k0 = 0; k0 < 1024; k0 += 32) {
    gload_lds16(Ab + (size_t)r0 * 1024 + k0 + c0, &As[e0]);
    gload_lds16(Ab + (size_t)(r0 + 64) * 1024 + k0 + c0, &As[e0 + 2048]);
    gload_lds16(Bb + (size_t)r0 * 1024 + k0 + c0, &Bs[e0]);
    gload_lds16(Bb + (size_t)(r0 + 64) * 1024 + k0 + c0, &Bs[e0 + 2048]);
    __syncthreads();
    bf16x8 af[4], bfg[4];
#pragma unroll
    for (int i = 0; i < 4; ++i)
      af[i] = *(const bf16x8*)&As[(wr * 64 + i * 16 + l15) * 32 + ko];
#pragma unroll
    for (int i = 0; i < 4; ++i)
      bfg[i] = *(const bf16x8*)&Bs[(wc * 64 + i * 16 + l15) * 32 + ko];
#pragma unroll
    for (int i = 0; i < 4; ++i)
#pragma unroll
      for (int j = 0; j < 4; ++j)
        acc[i][j] = __builtin_amdgcn_mfma_f32_16x16x32_bf16(af[i], bfg[j], acc[i][j], 0, 0, 0);
    __syncthreads();
  }

  const int mat = bcol >> 10;   // block-uniform: which of Q/K/V
#pragma unroll
  for (int i = 0; i < 4; ++i) {
    const int gm0 = brow + wr * 64 + i * 16 + ((lane >> 4) << 2);
    const int b = gm0 >> 11, s0 = gm0 & 2047;
#pragma unroll
    for (int j = 0; j < 4; ++j) {
      const int gn = bcol + wc * 64 + j * 16 + l15;
      const int col = gn & 1023;
      const int h = col >> 6, dd = col & 63;
      if (mat == 2) {
        const float bsv = bv[col];
        bf16x4 pk;
#pragma unroll
        for (int r = 0; r < 4; ++r) pk[r] = (bf16_t)(acc[i][j][r] + bsv);
        *(bf16x4*)&Vt[(((size_t)b * 16 + h) * 64 + dd) * 2048 + s0] = pk;
      } else {
        bf16_t* dst = mat == 0 ? Qb : Kb;
        const float bsv = (mat == 0 ? bq : bk)[col];
        const float scl = mat == 0 ? kQScale : 1.0f;
#pragma unroll
        for (int r = 0; r < 4; ++r)
          dst[((((size_t)b * 16 + h) * 2048 + (s0 + r)) * 64 + dd)] = (bf16_t)((acc[i][j][r] + bsv) * scl);
      }
    }
  }
}

// ---------------- K4: out-proj GEMM, 128x64 tile (512 blocks -> 2/CU) ----------------
__global__ __launch_bounds__(256) void gemm_out_k(
    const bf16_t* __restrict__ A, const bf16_t* __restrict__ Bw,
    float* __restrict__ outF, const float* __restrict__ bo) {
  __shared__ alignas(16) bf16_t As[128 * 32];
  __shared__ alignas(16) bf16_t Bs[64 * 32];
  const int tid = threadIdx.x;
  const int lane = tid & 63;
  const int w = tid >> 6;
  const int brow = blockIdx.y * 128, bcol = blockIdx.x * 64;
  const int l15 = lane & 15, ko = (lane >> 4) * 8;

  f32x4 acc[2][4] = {};
  const bf16_t* Ab = A + (size_t)brow * 1024;
  const bf16_t* Bb = Bw + (size_t)bcol * 1024;

  const int e0 = tid * 8;
  const int r0 = e0 >> 5, c0 = e0 & 31;   // A: rows 0..63 (+64); B: rows 0..63

  for (int k0 = 0; k0 < 1024; k0 += 32) {
    gload_lds16(Ab + (size_t)r0 * 1024 + k0 + c0, &As[e0]);
    gload_lds16(Ab + (size_t)(r0 + 64) * 1024 + k0 + c0, &As[e0 + 2048]);
    gload_lds16(Bb + (size_t)r0 * 1024 + k0 + c0, &Bs[e0]);
    __syncthreads();
    bf16x8 af[2], bfg[4];
#pragma unroll
    for (int i = 0; i < 2; ++i)
      af[i] = *(const bf16x8*)&As[(w * 32 + i * 16 + l15) * 32 + ko];
#pragma unroll
    for (int j = 0; j < 4; ++j)
      bfg[j] = *(const bf16x8*)&Bs[(j * 16 + l15) * 32 + ko];
#pragma unroll
    for (int i = 0; i < 2; ++i)
#pragma unroll
      for (int j = 0; j < 4; ++j)
        acc[i][j] = __builtin_amdgcn_mfma_f32_16x16x32_bf16(af[i], bfg[j], acc[i][j], 0, 0, 0);
    __syncthreads();
  }

#pragma unroll
  for (int i = 0; i < 2; ++i) {
    const int gm0 = brow + w * 32 + i * 16 + ((lane >> 4) << 2);
#pragma unroll
    for (int j = 0; j < 4; ++j) {
      const int gn = bcol + j * 16 + l15;
      const float bsv = bo[gn];
#pragma unroll
      for (int r = 0; r < 4; ++r)
        outF[(size_t)(gm0 + r) * 1024 + gn] = acc[i][j][r] + bsv;
    }
  }
}

// ---------------- K3: flash attention, 32x32 MFMA, LDS-shared K/V tiles ----------------
// Q [bh][s][64] (pre-scaled by log2e/8), K [bh][s][64], Vt [bh][64][s], all bf16.
// Block = 4 waves = 128 q-rows; K/V tiles (64 keys) staged once per block in LDS
// (double-buffered, global_load_lds w16, XOR-swizzled source+read per rule #21).
// S^T = mfma(K,Q) 32x32x16; in-register softmax (tree max, raw exp2, defer-rescale);
// P^T B-frags via cvt_pk + shfl_xor(32)+select. O^T = mfma(V^T, P^T).
__global__ __launch_bounds__(256, 2) void attn_k(
    const bf16_t* __restrict__ Qb, const bf16_t* __restrict__ Kb,
    const bf16_t* __restrict__ Vt, bf16_t* __restrict__ O) {
  __shared__ alignas(16) bf16_t Ksm[2][4096];   // [buf][64 rows][64 elems] swizzled
  __shared__ alignas(16) bf16_t Vsm[2][4096];   // [buf][64 d-rows][64 keys] swizzled
  const int tid = threadIdx.x, lane = tid & 63, w = tid >> 6;
  const int l31 = lane & 31, hi = lane >> 5;
  // bijective XCD-chunked swizzle: 512 blocks, 64 consecutive per XCD -> 4 heads/XCD L2
  const int work = (blockIdx.x & 7) * 64 + (blockIdx.x >> 3);
  const int bh = work >> 4;
  const int q0 = (work & 15) * 128 + w * 32;

  const bf16_t* Qp = Qb + ((size_t)bh * 2048 + q0) * 64;

  // ---- staging sources (per-thread, advancing). Tile = 8KB, 512 x 16B chunks.
  const int chunk0 = w * 64 + lane;
  const int srow = chunk0 >> 3;
  const int swzc = (chunk0 & 7) ^ (srow & 7);
  const char* srcK0 = (const char*)(Kb + (size_t)bh * 2048 * 64) + srow * 128 + swzc * 16;
  const char* srcK1 = srcK0 + 32 * 128;
  const char* srcV0 = (const char*)(Vt + (size_t)bh * 64 * 2048) + srow * 4096 + swzc * 16;
  const char* srcV1 = srcV0 + 32 * 4096;

  auto stage = [&](int buf) {   // 4 x gload_lds16; dest = wave-uniform base + lane*16
    bf16_t* kb = &Ksm[buf][w * 512];
    bf16_t* vb = &Vsm[buf][w * 512];
    gload_lds16((const bf16_t*)srcK0, kb);
    gload_lds16((const bf16_t*)srcK1, kb + 2048);
    gload_lds16((const bf16_t*)srcV0, vb);
    gload_lds16((const bf16_t*)srcV1, vb + 2048);
    srcK0 += 8192; srcK1 += 8192;
    srcV0 += 128;  srcV1 += 128;
  };

  // ---- fragment read bases (lane-constant; +st/dt*2048 +buf*4096 are immediates)
  const int xorv = l31 & 7;
  const bf16_t* kcb[4];
  const bf16_t* vcb[4];
#pragma unroll
  for (int j = 0; j < 4; ++j) {
    const int co = ((j * 2 + hi) ^ xorv) * 8;
    kcb[j] = &Ksm[0][l31 * 64 + co];
    vcb[j] = &Vsm[0][l31 * 64 + co];
  }

  // Q B-operand: col=q=l31, contraction d = ds*16 + hi*8 + j (map cancels vs K side)
  bf16x8 qf[4];
#pragma unroll
  for (int ds = 0; ds < 4; ++ds)
    qf[ds] = *(const bf16x8*)&Qp[(size_t)l31 * 64 + ds * 16 + hi * 8];

  f32x16 o0 = {}, o1 = {};
  float mx = -1e30f, li = 0.0f;

  auto tile_body = [&](int buf) {
    const int bo = buf * 4096;
    bf16x8 kf0[4], kf1[4];
#pragma unroll
    for (int ds = 0; ds < 4; ++ds) {
      kf0[ds] = *(const bf16x8*)(kcb[ds] + bo);
      kf1[ds] = *(const bf16x8*)(kcb[ds] + bo + 2048);
    }
    f32x16 s0 = {}, s1 = {};
    __builtin_amdgcn_s_setprio(1);
#pragma unroll
    for (int ds = 0; ds < 4; ++ds)
      s0 = __builtin_amdgcn_mfma_f32_32x32x16_bf16(kf0[ds], qf[ds], s0, 0, 0, 0);
#pragma unroll
    for (int ds = 0; ds < 4; ++ds)
      s1 = __builtin_amdgcn_mfma_f32_32x32x16_bf16(kf1[ds], qf[ds], s1, 0, 0, 0);
    __builtin_amdgcn_s_setprio(0);
    bf16x8 vf0[4], vf1[4];
#pragma unroll
    for (int ks = 0; ks < 4; ++ks) {
      vf0[ks] = *(const bf16x8*)(vcb[ks] + bo);
      vf1[ks] = *(const bf16x8*)(vcb[ks] + bo + 2048);
    }

    float m8[8];
#pragma unroll
    for (int r = 0; r < 8; ++r)
      m8[r] = fmaxf(fmaxf(s0[r], s0[r + 8]), fmaxf(s1[r], s1[r + 8]));
    float m4a = fmaxf(m8[0], m8[4]), m4b = fmaxf(m8[1], m8[5]);
    float m4c = fmaxf(m8[2], m8[6]), m4d = fmaxf(m8[3], m8[7]);
    float tmax = fmaxf(fmaxf(m4a, m4b), fmaxf(m4c, m4d));
    tmax = fmaxf(tmax, __shfl_xor(tmax, 32));

    if (__any(tmax > mx + 8.0f)) {
      const float mn = fmaxf(mx, tmax);
      const float corr = __builtin_amdgcn_exp2f(mx - mn);
      mx = mn;
      li *= corr;
#pragma unroll
      for (int r = 0; r < 16; ++r) { o0[r] *= corr; o1[r] *= corr; }
    }

    float ra = 0.f, rb = 0.f, rc = 0.f, rd = 0.f;
#pragma unroll
    for (int r = 0; r < 4; ++r) {
      float p0 = __builtin_amdgcn_exp2f(s0[r] - mx);       s0[r] = p0; ra += p0;
      float p1 = __builtin_amdgcn_exp2f(s0[r + 4] - mx);   s0[r + 4] = p1; rb += p1;
      float p2 = __builtin_amdgcn_exp2f(s0[r + 8] - mx);   s0[r + 8] = p2; rc += p2;
      float p3 = __builtin_amdgcn_exp2f(s0[r + 12] - mx);  s0[r + 12] = p3; rd += p3;
      float p4 = __builtin_amdgcn_exp2f(s1[r] - mx);       s1[r] = p4; ra += p4;
      float p5 = __builtin_amdgcn_exp2f(s1[r + 4] - mx);   s1[r + 4] = p5; rb += p5;
      float p6 = __builtin_amdgcn_exp2f(s1[r + 8] - mx);   s1[r + 8] = p6; rc += p6;
      float p7 = __builtin_amdgcn_exp2f(s1[r + 12] - mx);  s1[r + 12] = p7; rd += p7;
    }
    float rs = (ra + rb) + (rc + rd);
    rs += __shfl_xor(rs, 32);
    li += rs;

    uint32_t pw0[8], pw1[8];
#pragma unroll
    for (int g = 0; g < 4; ++g) {
      pw0[g * 2 + 0] = pk_bf16(s0[4 * g + 0], s0[4 * g + 1]);
      pw0[g * 2 + 1] = pk_bf16(s0[4 * g + 2], s0[4 * g + 3]);
      pw1[g * 2 + 0] = pk_bf16(s1[4 * g + 0], s1[4 * g + 1]);
      pw1[g * 2 + 1] = pk_bf16(s1[4 * g + 2], s1[4 * g + 3]);
    }

#pragma unroll
    for (int st = 0; st < 2; ++st) {
      uint32_t (&pw)[8] = st ? pw1 : pw0;
#pragma unroll
      for (int ks = 0; ks < 2; ++ks) {
        const uint32_t A0 = pw[(2 * ks) * 2 + 0], A1 = pw[(2 * ks) * 2 + 1];
        const uint32_t B0 = pw[(2 * ks + 1) * 2 + 0], B1 = pw[(2 * ks + 1) * 2 + 1];
        const uint32_t Z0 = hi ? A0 : B0;
        const uint32_t Z1 = hi ? A1 : B1;
        const uint32_t sZ0 = (uint32_t)__shfl_xor((int)Z0, 32);
        const uint32_t sZ1 = (uint32_t)__shfl_xor((int)Z1, 32);
        u32x4 fw;
        fw[0] = hi ? sZ0 : A0;
        fw[1] = hi ? sZ1 : A1;
        fw[2] = hi ? B0 : sZ0;
        fw[3] = hi ? B1 : sZ1;
        const bf16x8 pf = __builtin_bit_cast(bf16x8, fw);
        __builtin_amdgcn_s_setprio(1);
        o0 = __builtin_amdgcn_mfma_f32_32x32x16_bf16(vf0[st * 2 + ks], pf, o0, 0, 0, 0);
        o1 = __builtin_amdgcn_mfma_f32_32x32x16_bf16(vf1[st * 2 + ks], pf, o1, 0, 0, 0);
        __builtin_amdgcn_s_setprio(0);
      }
    }
  };

  stage(0);
  __syncthreads();
#pragma unroll 1
  for (int t = 0; t < 32; t += 2) {
    stage(1);
    tile_body(0);
    __syncthreads();
    if (t + 2 < 32) stage(0);
    tile_body(1);
    if (t + 2 < 32) __syncthreads();
  }

  // epilogue: O^T C-layout: col=q=l31, row d = 32dt + 8g + 4hi + r
  const int b = bh >> 4, h = bh & 15;
  const float inv = 1.0f / li;
  const size_t row = (size_t)b * 2048 + q0 + l31;
#pragma unroll
  for (int g = 0; g < 4; ++g) {
    bf16x4 p0, p1;
#pragma unroll
    for (int r = 0; r < 4; ++r) {
      p0[r] = (bf16_t)(o0[4 * g + r] * inv);
      p1[r] = (bf16_t)(o1[4 * g + r] * inv);
    }
    *(bf16x4*)&O[row * 1024 + h * 64 + 0  + g * 8 + hi * 4] = p0;
    *(bf16x4*)&O[row * 1024 + h * 64 + 32 + g * 8 + hi * 4] = p1;
  }
}

// ---------------- launch ----------------
extern "C" void kernel_launch(void* const* d_in, const int* in_sizes, int n_in,
                              void* d_out, int out_size, void* d_ws, size_t ws_size,
                              hipStream_t stream) {
  const float* x  = (const float*)d_in[0];
  const float* wq = (const float*)d_in[1];
  const float* bq = (const float*)d_in[2];
  const float* wk = (const float*)d_in[3];
  const float* bk = (const float*)d_in[4];
  const float* wv = (const float*)d_in[5];
  const float* bv = (const float*)d_in[6];
  const float* wo = (const float*)d_in[7];
  const float* bo = (const float*)d_in[8];
  float* out = (float*)d_out;

  if (ws_size < ((size_t)48 << 20)) return;  // need 48MB scratch
  char* ws = (char*)d_ws;
  bf16_t* xb  = (bf16_t*)(ws);                     // 8MB x bf16 [4096][1024]; reused as O after proj
  bf16_t* wT  = (bf16_t*)(ws + ((size_t)8 << 20)); // 6MB wqkvT [3072][1024] + 2MB woT
  bf16_t* woT = wT + (size_t)3072 * 1024;
  bf16_t* Qb  = (bf16_t*)(ws + ((size_t)16 << 20)); // [2][16][2048][64] bf16
  bf16_t* Kb  = (bf16_t*)(ws + ((size_t)24 << 20));
  bf16_t* Vt  = (bf16_t*)(ws + ((size_t)32 << 20)); // [2][16][64][2048]
  bf16_t* O   = xb;

  prep_k<<<dim3(16, 16, 5), 256, 0, stream>>>(x, xb, wq, wk, wv, wo, wT, woT);
  gemm_qkv_k<<<dim3(24, 32), 256, 0, stream>>>(xb, wT, Qb, Kb, Vt, bq, bk, bv);
  attn_k<<<512, 256, 0, stream>>>(Qb, Kb, Vt, O);
  gemm_out_k<<<dim3(16, 32), 256, 0, stream>>>(O, woT, out, bo);
}